// Round 3
// baseline (430.530 us; speedup 1.0000x reference)
//
#include <hip/hip_runtime.h>
#include <math.h>

constexpr int Bc = 2, Kc = 8, HWc = 16384;
constexpr float SCALE  = 0.17677669529663687f;  // 1/sqrt(32)
constexpr float INV127 = 1.0f / 127.0f;

// ws layout (floats). owt = combined (attn_w @ layer_w), stored d-major: owt[d][e].
// oke = same matrix e-major (channels only): oke[e][c], c<CK.
constexpr int OWQ1 = 0;
constexpr int OBQ1 = OWQ1 + 130 * 128;
constexpr int OWK1 = OBQ1 + 128;
constexpr int OBK1 = OWK1 + 130 * 128;
constexpr int OWQ2 = OBK1 + 128;
constexpr int OBQ2 = OWQ2 + 258 * 128;
constexpr int OWK2 = OBQ2 + 128;
constexpr int OBK2 = OWK2 + 258 * 128;
constexpr int OKE1 = OBK2 + 128;        // [128 e][128 c]
constexpr int OKE2 = OKE1 + 128 * 128;  // [128 e][256 c]

__device__ __forceinline__ unsigned bfpack(float a, float b) {
    unsigned ua = __float_as_uint(a); ua = (ua + 0x7FFFu + ((ua >> 16) & 1u)) >> 16;
    unsigned ub = __float_as_uint(b); ub = (ub + 0x7FFFu + ((ub >> 16) & 1u)) >> 16;
    return ua | (ub << 16);
}
__device__ __forceinline__ float bflo(unsigned u) { return __uint_as_float(u << 16); }
__device__ __forceinline__ float bfhi(unsigned u) { return __uint_as_float(u & 0xFFFF0000u); }

// ---------------------------------------------------------------------------
__global__ __launch_bounds__(128) void prep_kernel(
    const float* __restrict__ q1w, const float* __restrict__ q1b,
    const float* __restrict__ k1w, const float* __restrict__ k1b,
    const float* __restrict__ a1qw, const float* __restrict__ a1qb,
    const float* __restrict__ a1kw, const float* __restrict__ a1kb,
    const float* __restrict__ q2w, const float* __restrict__ q2b,
    const float* __restrict__ k2w, const float* __restrict__ k2b,
    const float* __restrict__ a2qw, const float* __restrict__ a2qb,
    const float* __restrict__ a2kw, const float* __restrict__ a2kb,
    float* __restrict__ ws)
{
    const int job = blockIdx.x / 260;
    const int d   = blockIdx.x % 260;
    const float *aw, *ab, *w, *wb;
    float *owt, *ob, *oke = nullptr;
    int D, CKj = 0;
    if (job == 0)      { aw=a1qw; ab=a1qb; w=q1w; wb=q1b; owt=ws+OWQ1; ob=ws+OBQ1; D=130; }
    else if (job == 1) { aw=a1kw; ab=a1kb; w=k1w; wb=k1b; owt=ws+OWK1; ob=ws+OBK1; D=130; oke=ws+OKE1; CKj=128; }
    else if (job == 2) { aw=a2qw; ab=a2qb; w=q2w; wb=q2b; owt=ws+OWQ2; ob=ws+OBQ2; D=258; }
    else               { aw=a2kw; ab=a2kb; w=k2w; wb=k2b; owt=ws+OWK2; ob=ws+OBK2; D=258; oke=ws+OKE2; CKj=256; }
    const int e = threadIdx.x;
    if (d < D) {
        float acc = 0.f;
        for (int f = 0; f < 128; ++f) acc += aw[e * 128 + f] * w[f * D + d];
        owt[d * 128 + e] = acc;
        if (oke && d < CKj) oke[e * CKj + d] = acc;
    } else if (d == D) {
        float acc = ab[e];
        for (int f = 0; f < 128; ++f) acc += aw[e * 128 + f] * wb[f];
        ob[e] = acc;
    }
}

// ---------------------------------------------------------------------------
// One block = (b, ks, hp): 16 queries (hw = r0..r0+15), 128 key positions
// (row hp). Query q's 8 keys are positions q*8..q*8+7.
// Factored scores: S[pos][h] = SCALE*( sum_c X[c][pos]*yq[h][c][q(pos)]
//                                      + ik*yi[h][q] + j(pos)*yj[h][q] + yb[h][q] )
// where yq[h][c][q] = sum_{e in head h} KW[e][c] * qa[e][q].
// LDS: sXq (phase-Q input) and sYQ (phase-Y output) are never live at the
// same time -> aliased in one union region.
// ---------------------------------------------------------------------------
template <int STAGE, int MINB>
__global__ __launch_bounds__(256, MINB) void stage_kernel(
    const float* __restrict__ HFs,   // [B][128][HW]
    const float* __restrict__ HFc,   // [B][K][128][HW]
    const float* __restrict__ Zc,    // [B][K][128][HW]
    const float* __restrict__ ws,
    const float* __restrict__ zst,   // z_star (stage 2 input)
    float* __restrict__ out)
{
    constexpr int CQ = (STAGE == 1) ? 128 : 256;
    constexpr int CK = (STAGE == 1) ? 128 : 256;
    constexpr int UNION_B = (CK * 17 * 8 > CQ * 20 * 4) ? CK * 17 * 8 : CQ * 20 * 4;
    constexpr int SMEM_B  = UNION_B + 128 * 20 * 4 + 192 * 4 + 64 * 9 * 4
                          + 4 * 128 * 4 + 16 * 8 * 4;

    const float* qwt = ws + ((STAGE == 1) ? OWQ1 : OWQ2);
    const float* qb  = ws + ((STAGE == 1) ? OBQ1 : OBQ2);
    const float* kwt = ws + ((STAGE == 1) ? OWK1 : OWK2);
    const float* kb  = ws + ((STAGE == 1) ? OBK1 : OBK2);
    const float* kwe = ws + ((STAGE == 1) ? OKE1 : OKE2);

    __shared__ __align__(16) char smem[SMEM_B];
    float* sXq  = (float*)smem;                        // [CQ][20] query features
    uint2* sYQ  = (uint2*)smem;                        // [CK][17] yq bf16x4 (aliased)
    float* sQA  = (float*)(smem + UNION_B);            // [128][20] qa
    float* sYX  = sQA + 128 * 20;                      // [3][4][16] yi/yj/yb
    float* sHW  = sYX + 192;                           // [64][9] per-(q,h) softmax w
    float* sSc  = sHW + 64 * 9;                        // [4][128] scores
    float* sAW  = sSc + 4 * 128;                       // [16][8] final attn weights

    const int t   = threadIdx.x;
    const int bid = blockIdx.x;
    const int b   = bid >> 10;
    const int rem = bid & 1023;
    const int ks  = rem >> 7;
    const int hp  = rem & 127;
    const int r0  = ks * 2048 + hp * 16;

    const float ik = (float)hp * INV127;
    const float iq = (float)(r0 >> 7) * INV127;
    const int   w0 = r0 & 127;

    // ---- stage query features into LDS
    {
        const int c = t >> 2, col = (t & 3) * 4;
        #pragma unroll
        for (int cb = 0; cb < CQ; cb += 64) {
            const int cc = cb + c;
            const float* src = (STAGE == 1 || cc < 128)
                ? HFs + ((size_t)(b * 128 + cc)) * HWc + r0 + col
                : zst + ((size_t)(b * 128 + cc - 128)) * HWc + r0 + col;
            *(float4*)&sXq[cc * 20 + col] = *(const float4*)src;
        }
    }
    __syncthreads();

    // ---- Phase Q: qa[e][q], thread = (e = t&127, qh = t>>7), 8 q each
    const int e  = t & 127;
    const int qh = t >> 7;
    {
        float aq[8];
        const float wi = qwt[(size_t)CQ * 128 + e];
        const float wj = qwt[(size_t)(CQ + 1) * 128 + e];
        const float bb = qb[e];
        #pragma unroll
        for (int j = 0; j < 8; ++j)
            aq[j] = bb + iq * wi + (float)(w0 + qh * 8 + j) * INV127 * wj;
        const float* wp = qwt + e;
        for (int cb = 0; cb < CQ; cb += 8) {
            float wv[8];
            #pragma unroll
            for (int u = 0; u < 8; ++u) wv[u] = wp[(size_t)(cb + u) * 128];
            #pragma unroll
            for (int u = 0; u < 8; ++u) {
                const float4 x0 = *(const float4*)&sXq[(cb + u) * 20 + qh * 8];
                const float4 x1 = *(const float4*)&sXq[(cb + u) * 20 + qh * 8 + 4];
                aq[0] += wv[u] * x0.x; aq[1] += wv[u] * x0.y;
                aq[2] += wv[u] * x0.z; aq[3] += wv[u] * x0.w;
                aq[4] += wv[u] * x1.x; aq[5] += wv[u] * x1.y;
                aq[6] += wv[u] * x1.z; aq[7] += wv[u] * x1.w;
            }
        }
        __syncthreads();   // all sXq reads done (union about to be overwritten)
        *(float4*)&sQA[e * 20 + qh * 8]     = make_float4(aq[0], aq[1], aq[2], aq[3]);
        *(float4*)&sQA[e * 20 + qh * 8 + 4] = make_float4(aq[4], aq[5], aq[6], aq[7]);
    }
    __syncthreads();

    // ---- Phase Y: yq[h][c][q] = sum_{e in h} KW[e][c] * qa[e][q]
    {
        const int co = t & 127;
        #pragma unroll
        for (int cpass = 0; cpass < CK / 128; ++cpass) {
            const int c = co + cpass * 128;
            float acc[4][8];
            #pragma unroll
            for (int h = 0; h < 4; ++h)
                #pragma unroll
                for (int j = 0; j < 8; ++j) acc[h][j] = 0.f;
            #pragma unroll
            for (int h = 0; h < 4; ++h) {
                #pragma unroll
                for (int eb = 0; eb < 32; eb += 8) {
                    float wv[8];
                    #pragma unroll
                    for (int u = 0; u < 8; ++u)
                        wv[u] = kwe[(size_t)(h * 32 + eb + u) * CK + c];
                    #pragma unroll
                    for (int u = 0; u < 8; ++u) {
                        const int e2 = h * 32 + eb + u;
                        const float4 q0 = *(const float4*)&sQA[e2 * 20 + qh * 8];
                        const float4 q1 = *(const float4*)&sQA[e2 * 20 + qh * 8 + 4];
                        acc[h][0] += wv[u] * q0.x; acc[h][1] += wv[u] * q0.y;
                        acc[h][2] += wv[u] * q0.z; acc[h][3] += wv[u] * q0.w;
                        acc[h][4] += wv[u] * q1.x; acc[h][5] += wv[u] * q1.y;
                        acc[h][6] += wv[u] * q1.z; acc[h][7] += wv[u] * q1.w;
                    }
                }
            }
            #pragma unroll
            for (int j = 0; j < 8; ++j) {
                uint2 u;
                u.x = bfpack(acc[0][j], acc[1][j]);
                u.y = bfpack(acc[2][j], acc[3][j]);
                sYQ[c * 17 + qh * 8 + j] = u;
            }
        }
        // coordinate / bias projections per head (tiny)
        if (t < 192) {
            const int q = t & 15, h = (t >> 4) & 3, which = t >> 6;
            const float* wrow = (which == 0) ? kwt + (size_t)CK * 128
                              : (which == 1) ? kwt + (size_t)(CK + 1) * 128
                                             : kb;
            float acc = 0.f;
            #pragma unroll
            for (int e32 = 0; e32 < 32; ++e32) {
                const int e2 = h * 32 + e32;
                acc += wrow[e2] * sQA[e2 * 20 + q];
            }
            sYX[(which * 4 + h) * 16 + q] = acc;
        }
    }
    __syncthreads();

    // ---- scores: per pos, dot X[:,pos] with yq[:, q(pos)], c split 2 halves
    float sacc[4] = {0.f, 0.f, 0.f, 0.f};
    {
        const int pos = t & 127, ch = t >> 7;
        const int q   = pos >> 3;
        const int c0  = ch * (CK / 2);
        const float* xp = (STAGE == 1 || ch == 0)
            ? HFc + (((size_t)(b * Kc + ks)) * 128 + c0) * HWc + hp * 128 + pos
            : zst + ((size_t)(b * 128)) * HWc + hp * 128 + pos;
        const uint2* yqp = &sYQ[c0 * 17 + q];
        for (int cb = 0; cb < CK / 2; cb += 16) {
            float xv[16];
            #pragma unroll
            for (int u = 0; u < 16; ++u)
                xv[u] = xp[(size_t)(cb + u) * HWc];
            #pragma unroll
            for (int u = 0; u < 16; ++u) {
                const uint2 uu = yqp[(cb + u) * 17];
                sacc[0] += xv[u] * bflo(uu.x); sacc[1] += xv[u] * bfhi(uu.x);
                sacc[2] += xv[u] * bflo(uu.y); sacc[3] += xv[u] * bfhi(uu.y);
            }
        }
        if (ch == 1) {
            #pragma unroll
            for (int h = 0; h < 4; ++h) sHW[pos * 4 + h + 64] = sacc[h];  // park in sHW tail? no:
        }
    }
    // NOTE: partials parked in sSc region to avoid an extra buffer:
    // rewrite: use sSc as staging for ch==1 partials first.
    __syncthreads();
    if (t < 128) {
        const int pos = t, q = pos >> 3;
        const float jk = (float)pos * INV127;
        #pragma unroll
        for (int h = 0; h < 4; ++h) {
            const float s = sacc[h] + sHW[pos * 4 + h + 64]
                          + ik * sYX[(0 * 4 + h) * 16 + q]
                          + jk * sYX[(1 * 4 + h) * 16 + q]
                          +      sYX[(2 * 4 + h) * 16 + q];
            sSc[h * 128 + pos] = s * SCALE;
        }
    }
    __syncthreads();

    // ---- softmax per (q, head) on 64 lanes, then combine on 16
    if (t < 64) {
        const int q = t & 15, h = t >> 4;
        float sc[8], m = -INFINITY;
        #pragma unroll
        for (int j = 0; j < 8; ++j) {
            sc[j] = sSc[h * 128 + q * 8 + j];
            m = fmaxf(m, sc[j]);
        }
        float sum = 0.f;
        #pragma unroll
        for (int j = 0; j < 8; ++j) { sc[j] = __expf(sc[j] - m); sum += sc[j]; }
        const float inv = 0.25f / sum;
        #pragma unroll
        for (int j = 0; j < 8; ++j) sHW[(h * 16 + q) * 9 + j] = sc[j] * inv;
    }
    __syncthreads();
    if (t < 16) {
        float at[8];
        float n2 = 0.f;
        #pragma unroll
        for (int j = 0; j < 8; ++j) {
            at[j] = sHW[(0 * 16 + t) * 9 + j] + sHW[(1 * 16 + t) * 9 + j]
                  + sHW[(2 * 16 + t) * 9 + j] + sHW[(3 * 16 + t) * 9 + j];
            n2 += at[j] * at[j];
        }
        const float nrm = fmaxf(sqrtf(n2), 1e-12f);
        #pragma unroll
        for (int j = 0; j < 8; ++j) sAW[t * 8 + j] = at[j] / nrm;
    }
    __syncthreads();

    // ---- PV: weighted sum of raw values, batched loads (4 ch per batch)
    {
        const int idx = t & 15, cg = t >> 4;
        const int c8  = cg * 8;
        const float4 a0 = *(const float4*)&sAW[idx * 8];
        const float4 a1 = *(const float4*)&sAW[idx * 8 + 4];
        const float* zb = Zc + (((size_t)(b * Kc + ks)) * 128 + c8) * HWc + hp * 128 + idx * 8;
        float* ob = out + ((size_t)(b * 128 + c8)) * HWc + r0 + idx;
        #pragma unroll
        for (int half = 0; half < 2; ++half) {
            float4 z0[4], z1[4];
            #pragma unroll
            for (int i = 0; i < 4; ++i) {
                z0[i] = *(const float4*)(zb + (size_t)(half * 4 + i) * HWc);
                z1[i] = *(const float4*)(zb + (size_t)(half * 4 + i) * HWc + 4);
            }
            #pragma unroll
            for (int i = 0; i < 4; ++i) {
                ob[(size_t)(half * 4 + i) * HWc] =
                    a0.x * z0[i].x + a0.y * z0[i].y + a0.z * z0[i].z + a0.w * z0[i].w +
                    a1.x * z1[i].x + a1.y * z1[i].y + a1.z * z1[i].z + a1.w * z1[i].w;
            }
        }
    }
}

// ---------------------------------------------------------------------------
extern "C" void kernel_launch(void* const* d_in, const int* in_sizes, int n_in,
                              void* d_out, int out_size, void* d_ws, size_t ws_size,
                              hipStream_t stream)
{
    const float* HFs = (const float*)d_in[0];
    const float* HFc = (const float*)d_in[1];
    const float* Zc  = (const float*)d_in[2];
    float* ws    = (float*)d_ws;
    float* zstar = (float*)d_out;
    float* zhat  = zstar + (size_t)Bc * 128 * HWc;

    prep_kernel<<<1040, 128, 0, stream>>>(
        (const float*)d_in[3],  (const float*)d_in[4],
        (const float*)d_in[5],  (const float*)d_in[6],
        (const float*)d_in[7],  (const float*)d_in[8],
        (const float*)d_in[9],  (const float*)d_in[10],
        (const float*)d_in[11], (const float*)d_in[12],
        (const float*)d_in[13], (const float*)d_in[14],
        (const float*)d_in[15], (const float*)d_in[16],
        (const float*)d_in[17], (const float*)d_in[18],
        ws);

    stage_kernel<1, 4><<<2048, 256, 0, stream>>>(HFs, HFc, Zc, ws, zstar, zstar);
    stage_kernel<2, 3><<<2048, 256, 0, stream>>>(HFs, HFc, Zc, ws, zstar, zhat);
}

// Round 4
// 257.902 us; speedup vs baseline: 1.6694x; 1.6694x over previous
//
#include <hip/hip_runtime.h>
#include <math.h>

constexpr int Bc = 2, Kc = 8, HWc = 16384;
constexpr float SCALE  = 0.17677669529663687f;  // 1/sqrt(32)
constexpr float INV127 = 1.0f / 127.0f;

// ws layout (floats). owt = combined (attn_w @ layer_w), stored d-major: owt[d][e].
// oke = same matrix e-major (channels only): oke[e][c], c<CK.
constexpr int OWQ1 = 0;
constexpr int OBQ1 = OWQ1 + 130 * 128;
constexpr int OWK1 = OBQ1 + 128;
constexpr int OBK1 = OWK1 + 130 * 128;
constexpr int OWQ2 = OBK1 + 128;
constexpr int OBQ2 = OWQ2 + 258 * 128;
constexpr int OWK2 = OBQ2 + 128;
constexpr int OBK2 = OWK2 + 258 * 128;
constexpr int OKE1 = OBK2 + 128;        // [128 e][128 c]
constexpr int OKE2 = OKE1 + 128 * 128;  // [128 e][256 c]

__device__ __forceinline__ unsigned bfpack(float a, float b) {
    unsigned ua = __float_as_uint(a); ua = (ua + 0x7FFFu + ((ua >> 16) & 1u)) >> 16;
    unsigned ub = __float_as_uint(b); ub = (ub + 0x7FFFu + ((ub >> 16) & 1u)) >> 16;
    return ua | (ub << 16);
}
__device__ __forceinline__ float bflo(unsigned u) { return __uint_as_float(u << 16); }
__device__ __forceinline__ float bfhi(unsigned u) { return __uint_as_float(u & 0xFFFF0000u); }

// ---------------------------------------------------------------------------
__global__ __launch_bounds__(128) void prep_kernel(
    const float* __restrict__ q1w, const float* __restrict__ q1b,
    const float* __restrict__ k1w, const float* __restrict__ k1b,
    const float* __restrict__ a1qw, const float* __restrict__ a1qb,
    const float* __restrict__ a1kw, const float* __restrict__ a1kb,
    const float* __restrict__ q2w, const float* __restrict__ q2b,
    const float* __restrict__ k2w, const float* __restrict__ k2b,
    const float* __restrict__ a2qw, const float* __restrict__ a2qb,
    const float* __restrict__ a2kw, const float* __restrict__ a2kb,
    float* __restrict__ ws)
{
    const int job = blockIdx.x / 260;
    const int d   = blockIdx.x % 260;
    const float *aw, *ab, *w, *wb;
    float *owt, *ob, *oke = nullptr;
    int D, CKj = 0;
    if (job == 0)      { aw=a1qw; ab=a1qb; w=q1w; wb=q1b; owt=ws+OWQ1; ob=ws+OBQ1; D=130; }
    else if (job == 1) { aw=a1kw; ab=a1kb; w=k1w; wb=k1b; owt=ws+OWK1; ob=ws+OBK1; D=130; oke=ws+OKE1; CKj=128; }
    else if (job == 2) { aw=a2qw; ab=a2qb; w=q2w; wb=q2b; owt=ws+OWQ2; ob=ws+OBQ2; D=258; }
    else               { aw=a2kw; ab=a2kb; w=k2w; wb=k2b; owt=ws+OWK2; ob=ws+OBK2; D=258; oke=ws+OKE2; CKj=256; }
    const int e = threadIdx.x;
    if (d < D) {
        float acc = 0.f;
        for (int f = 0; f < 128; ++f) acc += aw[e * 128 + f] * w[f * D + d];
        owt[d * 128 + e] = acc;
        if (oke && d < CKj) oke[e * CKj + d] = acc;
    } else if (d == D) {
        float acc = ab[e];
        for (int f = 0; f < 128; ++f) acc += aw[e * 128 + f] * wb[f];
        ob[e] = acc;
    }
}

// ---------------------------------------------------------------------------
// One block = (b, ks, hp): 16 queries (hw = r0..r0+15), 128 key positions
// (row hp). Query q's 8 keys are positions q*8..q*8+7.
// Factored scores: S[pos][h] = SCALE*( sum_c X[c][pos]*yq[h][c][q(pos)]
//                                      + ik*yi[h][q] + j(pos)*yj[h][q] + yb[h][q] )
// where yq[h][c][q] = sum_{e in head h} KW[e][c] * qa[e][q].
// sYQ holds only 128 channels at a time; stage 2 runs TWO Y->score passes
// reusing the buffer (score accumulators stay in registers).
// sXq (phase-Q input) aliases sYQ (never live simultaneously).
// ---------------------------------------------------------------------------
template <int STAGE>
__global__ __launch_bounds__(256) void stage_kernel(
    const float* __restrict__ HFs,   // [B][128][HW]
    const float* __restrict__ HFc,   // [B][K][128][HW]
    const float* __restrict__ Zc,    // [B][K][128][HW]
    const float* __restrict__ ws,
    const float* __restrict__ zst,   // z_star (stage 2 input)
    float* __restrict__ out)
{
    constexpr int CQ = (STAGE == 1) ? 128 : 256;
    constexpr int CK = (STAGE == 1) ? 128 : 256;
    constexpr int NP = CK / 128;                      // Y/score passes
    constexpr int UNION_B = (CQ * 20 * 4 > 128 * 17 * 8) ? CQ * 20 * 4 : 128 * 17 * 8;
    constexpr int SMEM_B  = UNION_B + 128 * 20 * 4 + 192 * 4 + 576 * 4
                          + 4 * 128 * 4 + 16 * 8 * 4;

    const float* qwt = ws + ((STAGE == 1) ? OWQ1 : OWQ2);
    const float* qb  = ws + ((STAGE == 1) ? OBQ1 : OBQ2);
    const float* kwt = ws + ((STAGE == 1) ? OWK1 : OWK2);
    const float* kb  = ws + ((STAGE == 1) ? OBK1 : OBK2);
    const float* kwe = ws + ((STAGE == 1) ? OKE1 : OKE2);

    __shared__ __align__(16) char smem[SMEM_B];
    float* sXq  = (float*)smem;                        // [CQ][20] query features
    uint2* sYQ  = (uint2*)smem;                        // [128][17] yq bf16x4 (aliased)
    float* sQA  = (float*)(smem + UNION_B);            // [128][20] qa
    float* sYX  = sQA + 128 * 20;                      // [3][4][16] yi/yj/yb
    float* sHW  = sYX + 192;                           // [576] partials / softmax w
    float* sSc  = sHW + 576;                           // [4][128] scores
    float* sAW  = sSc + 4 * 128;                       // [16][8] final attn weights

    const int t   = threadIdx.x;
    const int bid = blockIdx.x;
    const int b   = bid >> 10;
    const int rem = bid & 1023;
    const int ks  = rem >> 7;
    const int hp  = rem & 127;
    const int r0  = ks * 2048 + hp * 16;

    const float ik = (float)hp * INV127;
    const float iq = (float)(r0 >> 7) * INV127;
    const int   w0 = r0 & 127;

    // ---- stage query features into LDS
    {
        const int c = t >> 2, col = (t & 3) * 4;
        #pragma unroll
        for (int cb = 0; cb < CQ; cb += 64) {
            const int cc = cb + c;
            const float* src = (STAGE == 1 || cc < 128)
                ? HFs + ((size_t)(b * 128 + cc)) * HWc + r0 + col
                : zst + ((size_t)(b * 128 + cc - 128)) * HWc + r0 + col;
            *(float4*)&sXq[cc * 20 + col] = *(const float4*)src;
        }
    }
    __syncthreads();

    // ---- Phase Q: qa[e][q], thread = (e = t&127, qh = t>>7), 8 q each
    const int e  = t & 127;
    const int qh = t >> 7;
    {
        float aq[8];
        const float wi = qwt[(size_t)CQ * 128 + e];
        const float wj = qwt[(size_t)(CQ + 1) * 128 + e];
        const float bb = qb[e];
        #pragma unroll
        for (int j = 0; j < 8; ++j)
            aq[j] = bb + iq * wi + (float)(w0 + qh * 8 + j) * INV127 * wj;
        const float* wp = qwt + e;
        #pragma unroll 4
        for (int c = 0; c < CQ; ++c) {
            const float  w  = wp[(size_t)c * 128];
            const float4 x0 = *(const float4*)&sXq[c * 20 + qh * 8];
            const float4 x1 = *(const float4*)&sXq[c * 20 + qh * 8 + 4];
            aq[0] += w * x0.x; aq[1] += w * x0.y; aq[2] += w * x0.z; aq[3] += w * x0.w;
            aq[4] += w * x1.x; aq[5] += w * x1.y; aq[6] += w * x1.z; aq[7] += w * x1.w;
        }
        __syncthreads();   // all sXq reads done (union region reused below)
        *(float4*)&sQA[e * 20 + qh * 8]     = make_float4(aq[0], aq[1], aq[2], aq[3]);
        *(float4*)&sQA[e * 20 + qh * 8 + 4] = make_float4(aq[4], aq[5], aq[6], aq[7]);
    }
    __syncthreads();

    // ---- NP passes of { Phase Y (128 ch) ; score accumulate } ----
    float sacc[4] = {0.f, 0.f, 0.f, 0.f};
    const int pos = t & 127;
    const int ch  = t >> 7;
    const int q   = pos >> 3;

    #pragma unroll
    for (int p = 0; p < NP; ++p) {
        // Phase Y: yq[h][c][q] for c in [p*128, p*128+128)
        {
            const int co = t & 127;
            const int c  = p * 128 + co;
            float acc[4][8];
            #pragma unroll
            for (int h = 0; h < 4; ++h)
                #pragma unroll
                for (int j = 0; j < 8; ++j) acc[h][j] = 0.f;
            #pragma unroll
            for (int h = 0; h < 4; ++h) {
                #pragma unroll 4
                for (int e32 = 0; e32 < 32; ++e32) {
                    const int e2 = h * 32 + e32;
                    const float  w  = kwe[(size_t)e2 * CK + c];
                    const float4 q0 = *(const float4*)&sQA[e2 * 20 + qh * 8];
                    const float4 q1 = *(const float4*)&sQA[e2 * 20 + qh * 8 + 4];
                    acc[h][0] += w * q0.x; acc[h][1] += w * q0.y;
                    acc[h][2] += w * q0.z; acc[h][3] += w * q0.w;
                    acc[h][4] += w * q1.x; acc[h][5] += w * q1.y;
                    acc[h][6] += w * q1.z; acc[h][7] += w * q1.w;
                }
            }
            #pragma unroll
            for (int j = 0; j < 8; ++j) {
                uint2 u;
                u.x = bfpack(acc[0][j], acc[1][j]);
                u.y = bfpack(acc[2][j], acc[3][j]);
                sYQ[co * 17 + qh * 8 + j] = u;
            }
        }
        // coordinate / bias projections per head (once)
        if (p == 0 && t < 192) {
            const int qq = t & 15, h = (t >> 4) & 3, which = t >> 6;
            const float* wrow = (which == 0) ? kwt + (size_t)CK * 128
                              : (which == 1) ? kwt + (size_t)(CK + 1) * 128
                                             : kb;
            float acc = 0.f;
            #pragma unroll
            for (int e32 = 0; e32 < 32; ++e32) {
                const int e2 = h * 32 + e32;
                acc += wrow[e2] * sQA[e2 * 20 + qq];
            }
            sYX[(which * 4 + h) * 16 + qq] = acc;
        }
        __syncthreads();

        // score accumulate: this thread covers c in [p*128+ch*64, +64)
        {
            const int cs = p * 128 + ch * 64;
            const float* xp = (STAGE == 1 || cs < 128)
                ? HFc + (((size_t)(b * Kc + ks)) * 128 + cs) * HWc + hp * 128 + pos
                : zst + ((size_t)(b * 128 + (cs - 128))) * HWc + hp * 128 + pos;
            const uint2* yqp = &sYQ[(ch * 64) * 17 + q];
            #pragma unroll 8
            for (int cc = 0; cc < 64; ++cc) {
                const float x = xp[(size_t)cc * HWc];
                const uint2 u = yqp[cc * 17];
                sacc[0] += x * bflo(u.x); sacc[1] += x * bfhi(u.x);
                sacc[2] += x * bflo(u.y); sacc[3] += x * bfhi(u.y);
            }
        }
        __syncthreads();   // sYQ consumed; safe to overwrite next pass
    }

    // ---- combine halves, add coordinate/bias terms, scale
    if (ch == 1) {
        #pragma unroll
        for (int h = 0; h < 4; ++h) sHW[pos * 4 + h] = sacc[h];
    }
    __syncthreads();
    if (t < 128) {
        const float jk = (float)pos * INV127;
        #pragma unroll
        for (int h = 0; h < 4; ++h) {
            const float s = sacc[h] + sHW[pos * 4 + h]
                          + ik * sYX[(0 * 4 + h) * 16 + q]
                          + jk * sYX[(1 * 4 + h) * 16 + q]
                          +      sYX[(2 * 4 + h) * 16 + q];
            sSc[h * 128 + pos] = s * SCALE;
        }
    }
    __syncthreads();

    // ---- softmax per (q, head) on 64 lanes, then combine on 16
    if (t < 64) {
        const int qq = t & 15, h = t >> 4;
        float sc[8], m = -INFINITY;
        #pragma unroll
        for (int j = 0; j < 8; ++j) {
            sc[j] = sSc[h * 128 + qq * 8 + j];
            m = fmaxf(m, sc[j]);
        }
        float sum = 0.f;
        #pragma unroll
        for (int j = 0; j < 8; ++j) { sc[j] = __expf(sc[j] - m); sum += sc[j]; }
        const float inv = 0.25f / sum;
        #pragma unroll
        for (int j = 0; j < 8; ++j) sHW[(h * 16 + qq) * 9 + j] = sc[j] * inv;
    }
    __syncthreads();
    if (t < 16) {
        float at[8];
        float n2 = 0.f;
        #pragma unroll
        for (int j = 0; j < 8; ++j) {
            at[j] = sHW[(0 * 16 + t) * 9 + j] + sHW[(1 * 16 + t) * 9 + j]
                  + sHW[(2 * 16 + t) * 9 + j] + sHW[(3 * 16 + t) * 9 + j];
            n2 += at[j] * at[j];
        }
        const float nrm = fmaxf(sqrtf(n2), 1e-12f);
        #pragma unroll
        for (int j = 0; j < 8; ++j) sAW[t * 8 + j] = at[j] / nrm;
    }
    __syncthreads();

    // ---- PV: weighted sum of raw values (direct coalesced global reads)
    {
        const int idx = t & 15, cg = t >> 4;
        const int c8  = cg * 8;
        const float4 a0 = *(const float4*)&sAW[idx * 8];
        const float4 a1 = *(const float4*)&sAW[idx * 8 + 4];
        const float* zb = Zc + (((size_t)(b * Kc + ks)) * 128 + c8) * HWc + hp * 128 + idx * 8;
        float* ob = out + ((size_t)(b * 128 + c8)) * HWc + r0 + idx;
        #pragma unroll
        for (int i = 0; i < 8; ++i) {
            const float4 z0 = *(const float4*)(zb + (size_t)i * HWc);
            const float4 z1 = *(const float4*)(zb + (size_t)i * HWc + 4);
            ob[(size_t)i * HWc] =
                a0.x * z0.x + a0.y * z0.y + a0.z * z0.z + a0.w * z0.w +
                a1.x * z1.x + a1.y * z1.y + a1.z * z1.z + a1.w * z1.w;
        }
    }
}

// ---------------------------------------------------------------------------
extern "C" void kernel_launch(void* const* d_in, const int* in_sizes, int n_in,
                              void* d_out, int out_size, void* d_ws, size_t ws_size,
                              hipStream_t stream)
{
    const float* HFs = (const float*)d_in[0];
    const float* HFc = (const float*)d_in[1];
    const float* Zc  = (const float*)d_in[2];
    float* ws    = (float*)d_ws;
    float* zstar = (float*)d_out;
    float* zhat  = zstar + (size_t)Bc * 128 * HWc;

    prep_kernel<<<1040, 128, 0, stream>>>(
        (const float*)d_in[3],  (const float*)d_in[4],
        (const float*)d_in[5],  (const float*)d_in[6],
        (const float*)d_in[7],  (const float*)d_in[8],
        (const float*)d_in[9],  (const float*)d_in[10],
        (const float*)d_in[11], (const float*)d_in[12],
        (const float*)d_in[13], (const float*)d_in[14],
        (const float*)d_in[15], (const float*)d_in[16],
        (const float*)d_in[17], (const float*)d_in[18],
        ws);

    stage_kernel<1><<<2048, 256, 0, stream>>>(HFs, HFc, Zc, ws, zstar, zstar);
    stage_kernel<2><<<2048, 256, 0, stream>>>(HFs, HFc, Zc, ws, zstar, zhat);
}

// Round 5
// 151.504 us; speedup vs baseline: 2.8417x; 1.7023x over previous
//
#include <hip/hip_runtime.h>
#include <math.h>

constexpr int Bc = 2, Kc = 8, HWc = 16384;
constexpr float SCALE  = 0.17677669529663687f;  // 1/sqrt(32)
constexpr float INV127 = 1.0f / 127.0f;

using short8 = __attribute__((ext_vector_type(8))) short;
using f32x4  = __attribute__((ext_vector_type(4))) float;

// ws layout (floats). owt = combined (attn_w @ layer_w), d-major: owt[d][e].
constexpr int OWQ1 = 0;
constexpr int OBQ1 = OWQ1 + 130 * 128;
constexpr int OWK1 = OBQ1 + 128;
constexpr int OBK1 = OWK1 + 130 * 128;
constexpr int OWQ2 = OBK1 + 128;
constexpr int OBQ2 = OWQ2 + 258 * 128;
constexpr int OWK2 = OBQ2 + 128;
constexpr int OBK2 = OWK2 + 258 * 128;
constexpr int OPACK = OBK2 + 128;       // short region: packed MFMA A-fragments
// pack sub-offsets (in shorts): Q1[8et][4kt], Q2[8][8], Y1[8ct][4h], Y2[16ct][4h]
constexpr int PQ1 = 0;
constexpr int PQ2 = PQ1 + 32 * 512;
constexpr int PY1 = PQ2 + 64 * 512;
constexpr int PY2 = PY1 + 32 * 512;

__device__ __forceinline__ unsigned bfpack(float a, float b) {
    unsigned ua = __float_as_uint(a); ua = (ua + 0x7FFFu + ((ua >> 16) & 1u)) >> 16;
    unsigned ub = __float_as_uint(b); ub = (ub + 0x7FFFu + ((ub >> 16) & 1u)) >> 16;
    return ua | (ub << 16);
}
__device__ __forceinline__ short bf1(float a) {
    unsigned ua = __float_as_uint(a); ua = (ua + 0x7FFFu + ((ua >> 16) & 1u)) >> 16;
    return (short)ua;
}
__device__ __forceinline__ float bflo(unsigned u) { return __uint_as_float(u << 16); }
__device__ __forceinline__ float bfhi(unsigned u) { return __uint_as_float(u & 0xFFFF0000u); }
__device__ __forceinline__ float bf2f(short s) {
    return __uint_as_float(((unsigned)(unsigned short)s) << 16);
}

// ---------------------------------------------------------------------------
// prep: combined weights Wc = a_w @ w (transposed: owt[d*128+e]), combined bias
// ---------------------------------------------------------------------------
__global__ __launch_bounds__(128) void prep_kernel(
    const float* __restrict__ q1w, const float* __restrict__ q1b,
    const float* __restrict__ k1w, const float* __restrict__ k1b,
    const float* __restrict__ a1qw, const float* __restrict__ a1qb,
    const float* __restrict__ a1kw, const float* __restrict__ a1kb,
    const float* __restrict__ q2w, const float* __restrict__ q2b,
    const float* __restrict__ k2w, const float* __restrict__ k2b,
    const float* __restrict__ a2qw, const float* __restrict__ a2qb,
    const float* __restrict__ a2kw, const float* __restrict__ a2kb,
    float* __restrict__ ws)
{
    const int job = blockIdx.x / 260;
    const int d   = blockIdx.x % 260;
    const float *aw, *ab, *w, *wb;
    float *owt, *ob;
    int D;
    if (job == 0)      { aw=a1qw; ab=a1qb; w=q1w; wb=q1b; owt=ws+OWQ1; ob=ws+OBQ1; D=130; }
    else if (job == 1) { aw=a1kw; ab=a1kb; w=k1w; wb=k1b; owt=ws+OWK1; ob=ws+OBK1; D=130; }
    else if (job == 2) { aw=a2qw; ab=a2qb; w=q2w; wb=q2b; owt=ws+OWQ2; ob=ws+OBQ2; D=258; }
    else               { aw=a2kw; ab=a2kb; w=k2w; wb=k2b; owt=ws+OWK2; ob=ws+OBK2; D=258; }
    const int e = threadIdx.x;
    if (d < D) {
        float acc = 0.f;
        for (int f = 0; f < 128; ++f) acc += aw[e * 128 + f] * w[f * D + d];
        owt[d * 128 + e] = acc;
    } else if (d == D) {
        float acc = ab[e];
        for (int f = 0; f < 128; ++f) acc += aw[e * 128 + f] * wb[f];
        ob[e] = acc;
    }
}

// ---------------------------------------------------------------------------
// pack: MFMA A-fragments (bf16), native layout: element(lane,idx) = A[i][k],
// i = lane&15, k = 8*(lane>>4)+idx.
//   Q-pack: A[i=e_loc][k=c_loc] = owt[(kt*32+k)*128 + et*16+i]
//   Y-pack: A[i=c_loc][k=e_loc] = owt[(ct*16+i)*128 + h*32+k]
// ---------------------------------------------------------------------------
__global__ __launch_bounds__(64) void pack_kernel(float* __restrict__ ws)
{
    short* pk = (short*)(ws + OPACK);
    const int l = threadIdx.x, bid = blockIdx.x;
    const float* w;
    short* dst;
    short v[8];
    if (bid < 32) {                       // Q1 (NKT=4)
        const int et = bid >> 2, kt = bid & 3;
        w = ws + OWQ1;
        dst = pk + PQ1 + ((size_t)(et * 4 + kt) * 64 + l) * 8;
        #pragma unroll
        for (int idx = 0; idx < 8; ++idx)
            v[idx] = bf1(w[(kt * 32 + (l >> 4) * 8 + idx) * 128 + et * 16 + (l & 15)]);
    } else if (bid < 96) {                // Q2 (NKT=8)
        const int b2 = bid - 32, et = b2 >> 3, kt = b2 & 7;
        w = ws + OWQ2;
        dst = pk + PQ2 + ((size_t)(et * 8 + kt) * 64 + l) * 8;
        #pragma unroll
        for (int idx = 0; idx < 8; ++idx)
            v[idx] = bf1(w[(kt * 32 + (l >> 4) * 8 + idx) * 128 + et * 16 + (l & 15)]);
    } else if (bid < 128) {               // Y1 (8 ct x 4 h)
        const int b2 = bid - 96, ct = b2 >> 2, h = b2 & 3;
        w = ws + OWK1;
        dst = pk + PY1 + ((size_t)(ct * 4 + h) * 64 + l) * 8;
        #pragma unroll
        for (int idx = 0; idx < 8; ++idx)
            v[idx] = bf1(w[(ct * 16 + (l & 15)) * 128 + h * 32 + (l >> 4) * 8 + idx]);
    } else {                              // Y2 (16 ct x 4 h)
        const int b2 = bid - 128, ct = b2 >> 2, h = b2 & 3;
        w = ws + OWK2;
        dst = pk + PY2 + ((size_t)(ct * 4 + h) * 64 + l) * 8;
        #pragma unroll
        for (int idx = 0; idx < 8; ++idx)
            v[idx] = bf1(w[(ct * 16 + (l & 15)) * 128 + h * 32 + (l >> 4) * 8 + idx]);
    }
    uint4 u;
    u.x = (unsigned)(unsigned short)v[0] | ((unsigned)(unsigned short)v[1] << 16);
    u.y = (unsigned)(unsigned short)v[2] | ((unsigned)(unsigned short)v[3] << 16);
    u.z = (unsigned)(unsigned short)v[4] | ((unsigned)(unsigned short)v[5] << 16);
    u.w = (unsigned)(unsigned short)v[6] | ((unsigned)(unsigned short)v[7] << 16);
    *(uint4*)dst = u;
}

// ---------------------------------------------------------------------------
// Fused stage kernel with MFMA projection phases.
// Block = (b, ks, hp): 16 queries (hw r0..r0+15), 128 key positions (row hp).
// Phase Q (MFMA): qa[128e][16q] = Wq^T(256c x 128e) * Xq(256c x 16q)
// Phase Y (MFMA): yq[h][c][q]   = KW_h^T * qa_h   (K=32 per head = 1 MFMA)
// Score (VALU):   S[pos][h] = sum_c X[c][pos]*yq[h][c][q(pos)] + coords
// LDS: Xq frags (8KB) alias sYQ (17KB); qa frags separate (4KB).
// ---------------------------------------------------------------------------
template <int STAGE>
__global__ __launch_bounds__(256) void stage_kernel(
    const float* __restrict__ HFs,   // [B][128][HW]
    const float* __restrict__ HFc,   // [B][K][128][HW]
    const float* __restrict__ Zc,    // [B][K][128][HW]
    const float* __restrict__ ws,
    const float* __restrict__ zst,   // z_star (stage 2 input)
    float* __restrict__ out)
{
    constexpr int CQ  = (STAGE == 1) ? 128 : 256;
    constexpr int CK  = CQ;
    constexpr int NP  = CK / 128;      // Y/score passes
    constexpr int NKT = CQ / 32;       // phase-Q k-tiles

    const float* qwt = ws + ((STAGE == 1) ? OWQ1 : OWQ2);
    const float* qb_ = ws + ((STAGE == 1) ? OBQ1 : OBQ2);
    const float* kwt = ws + ((STAGE == 1) ? OWK1 : OWK2);
    const float* kb_ = ws + ((STAGE == 1) ? OBK1 : OBK2);
    const short* pk  = (const short*)(ws + OPACK);
    const short* aQ  = pk + ((STAGE == 1) ? PQ1 : PQ2);
    const short* aY  = pk + ((STAGE == 1) ? PY1 : PY2);

    // smem: [0,17408) union{ sXF frags (<=8KB) , sYQ [128][17] uint2 }
    //       [17408,21504) sQF qa-frags ; then sYX 768, sHW 2304, sSc 2048, sAW 512
    __shared__ __align__(16) char smem[27136];
    short* sXF = (short*)smem;
    uint2* sYQ = (uint2*)smem;
    short* sQF = (short*)(smem + 17408);
    float* sYX = (float*)(smem + 21504);
    float* sHW = sYX + 192;
    float* sSc = sHW + 576;
    float* sAW = sSc + 512;

    const int t   = threadIdx.x;
    const int l   = t & 63;
    const int wv  = t >> 6;
    const int bid = blockIdx.x;
    const int b   = bid >> 10;
    const int rem = bid & 1023;
    const int ks  = rem >> 7;
    const int hp  = rem & 127;
    const int r0  = ks * 2048 + hp * 16;

    const float ik = (float)hp * INV127;
    const float iq = (float)(r0 >> 7) * INV127;
    const int   w0 = r0 & 127;

    // ---- stage Xq into LDS in B-fragment order (bf16) ----
    {
        const int q = t & 15, cq = t >> 4;
        #pragma unroll
        for (int r = 0; r < CQ / 64; ++r) {
            const int c0 = cq * 4 + r * 64;
            const float* src = (STAGE == 1 || c0 < 128)
                ? HFs + ((size_t)(b * 128 + c0)) * HWc + r0 + q
                : zst + ((size_t)(b * 128 + (c0 - 128))) * HWc + r0 + q;
            const float x0 = src[0];
            const float x1 = src[(size_t)HWc];
            const float x2 = src[(size_t)2 * HWc];
            const float x3 = src[(size_t)3 * HWc];
            uint2 u; u.x = bfpack(x0, x1); u.y = bfpack(x2, x3);
            const int kt = c0 >> 5, g = (c0 & 31) >> 3, idx0 = c0 & 7;
            *(uint2*)&sXF[kt * 512 + (q + 16 * g) * 8 + idx0] = u;
        }
    }
    __syncthreads();

    // ---- Phase Q (MFMA): wave wv owns e-tiles {2wv, 2wv+1} ----
    {
        const float jqv = (float)(w0 + (l & 15)) * INV127;
        f32x4 acc0, acc1;
        #pragma unroll
        for (int r = 0; r < 4; ++r) {
            const int e0 = (wv * 2 + 0) * 16 + (l >> 4) * 4 + r;
            const int e1 = (wv * 2 + 1) * 16 + (l >> 4) * 4 + r;
            acc0[r] = qb_[e0] + iq * qwt[(size_t)CQ * 128 + e0]
                             + jqv * qwt[(size_t)(CQ + 1) * 128 + e0];
            acc1[r] = qb_[e1] + iq * qwt[(size_t)CQ * 128 + e1]
                             + jqv * qwt[(size_t)(CQ + 1) * 128 + e1];
        }
        #pragma unroll
        for (int kt = 0; kt < NKT; ++kt) {
            const short8 bfr = *(const short8*)&sXF[kt * 512 + l * 8];
            const short8 a0 = *(const short8*)&aQ[(((wv * 2 + 0) * NKT + kt) * 64 + l) * 8];
            const short8 a1 = *(const short8*)&aQ[(((wv * 2 + 1) * NKT + kt) * 64 + l) * 8];
            acc0 = __builtin_amdgcn_mfma_f32_16x16x32_bf16(a0, bfr, acc0, 0, 0, 0);
            acc1 = __builtin_amdgcn_mfma_f32_16x16x32_bf16(a1, bfr, acc1, 0, 0, 0);
        }
        // write qa (bf16) in B-fragment order: qaF[kt=e>>5][lane][idx=e&7]
        #pragma unroll
        for (int m = 0; m < 2; ++m) {
            const f32x4 a = m ? acc1 : acc0;
            const int e0 = (wv * 2 + m) * 16 + (l >> 4) * 4;
            const int kt = e0 >> 5, g = (e0 & 31) >> 3, idx0 = e0 & 7;
            uint2 u; u.x = bfpack(a[0], a[1]); u.y = bfpack(a[2], a[3]);
            *(uint2*)&sQF[kt * 512 + ((l & 15) + 16 * g) * 8 + idx0] = u;
        }
    }
    __syncthreads();

    // ---- coordinate / bias projections per head (reads qa bf16) ----
    if (t < 192) {
        const int q = t & 15, h = (t >> 4) & 3, which = t >> 6;
        const float* wrow = (which == 0) ? kwt + (size_t)CK * 128
                          : (which == 1) ? kwt + (size_t)(CK + 1) * 128
                                         : kb_;
        float acc = 0.f;
        #pragma unroll
        for (int e32 = 0; e32 < 32; ++e32) {
            const int e2 = h * 32 + e32;
            const int g = (e2 & 31) >> 3, idx = e2 & 7;
            acc += wrow[e2] * bf2f(sQF[h * 512 + (q + 16 * g) * 8 + idx]);
        }
        sYX[(which * 4 + h) * 16 + q] = acc;
    }

    // ---- load qa B-fragments (one per head) ----
    short8 bq0 = *(const short8*)&sQF[0 * 512 + l * 8];
    short8 bq1 = *(const short8*)&sQF[1 * 512 + l * 8];
    short8 bq2 = *(const short8*)&sQF[2 * 512 + l * 8];
    short8 bq3 = *(const short8*)&sQF[3 * 512 + l * 8];

    // ---- NP passes of { Phase Y (MFMA, 128 ch) ; score accumulate } ----
    float sacc[4] = {0.f, 0.f, 0.f, 0.f};
    const int pos = t & 127;
    const int ch  = t >> 7;
    const int q   = pos >> 3;
    const f32x4 zf = {0.f, 0.f, 0.f, 0.f};

    #pragma unroll
    for (int p = 0; p < NP; ++p) {
        // Phase Y: wave wv owns local c-tiles {2wv, 2wv+1}
        #pragma unroll
        for (int m = 0; m < 2; ++m) {
            const int ctl = wv * 2 + m;
            const int ct  = p * 8 + ctl;
            f32x4 d0, d1, d2, d3;
            {
                const short8 a0 = *(const short8*)&aY[(((ct * 4) + 0) * 64 + l) * 8];
                const short8 a1 = *(const short8*)&aY[(((ct * 4) + 1) * 64 + l) * 8];
                const short8 a2 = *(const short8*)&aY[(((ct * 4) + 2) * 64 + l) * 8];
                const short8 a3 = *(const short8*)&aY[(((ct * 4) + 3) * 64 + l) * 8];
                d0 = __builtin_amdgcn_mfma_f32_16x16x32_bf16(a0, bq0, zf, 0, 0, 0);
                d1 = __builtin_amdgcn_mfma_f32_16x16x32_bf16(a1, bq1, zf, 0, 0, 0);
                d2 = __builtin_amdgcn_mfma_f32_16x16x32_bf16(a2, bq2, zf, 0, 0, 0);
                d3 = __builtin_amdgcn_mfma_f32_16x16x32_bf16(a3, bq3, zf, 0, 0, 0);
            }
            #pragma unroll
            for (int r = 0; r < 4; ++r) {
                const int cl = ctl * 16 + (l >> 4) * 4 + r;
                uint2 u;
                u.x = bfpack(d0[r], d1[r]);
                u.y = bfpack(d2[r], d3[r]);
                sYQ[cl * 17 + (l & 15)] = u;
            }
        }
        __syncthreads();

        // score accumulate: this thread covers c in [p*128 + ch*64, +64)
        {
            const int cs = p * 128 + ch * 64;
            const float* xp = (STAGE == 1 || cs < 128)
                ? HFc + (((size_t)(b * Kc + ks)) * 128 + cs) * HWc + hp * 128 + pos
                : zst + ((size_t)(b * 128 + (cs - 128))) * HWc + hp * 128 + pos;
            const uint2* yqp = &sYQ[(ch * 64) * 17 + q];
            #pragma unroll 8
            for (int cc = 0; cc < 64; ++cc) {
                const float x = xp[(size_t)cc * HWc];
                const uint2 u = yqp[cc * 17];
                sacc[0] += x * bflo(u.x); sacc[1] += x * bfhi(u.x);
                sacc[2] += x * bflo(u.y); sacc[3] += x * bfhi(u.y);
            }
        }
        __syncthreads();   // sYQ consumed; safe to overwrite next pass
    }

    // ---- combine halves, add coordinate/bias terms, scale ----
    if (ch == 1) {
        #pragma unroll
        for (int h = 0; h < 4; ++h) sHW[pos * 4 + h] = sacc[h];
    }
    __syncthreads();
    if (t < 128) {
        const float jk = (float)pos * INV127;
        #pragma unroll
        for (int h = 0; h < 4; ++h) {
            const float s = sacc[h] + sHW[pos * 4 + h]
                          + ik * sYX[(0 * 4 + h) * 16 + q]
                          + jk * sYX[(1 * 4 + h) * 16 + q]
                          +      sYX[(2 * 4 + h) * 16 + q];
            sSc[h * 128 + pos] = s * SCALE;
        }
    }
    __syncthreads();

    // ---- softmax per (q, head) on 64 lanes, then combine on 16 ----
    if (t < 64) {
        const int qq = t & 15, h = t >> 4;
        float sc[8], m = -INFINITY;
        #pragma unroll
        for (int j = 0; j < 8; ++j) {
            sc[j] = sSc[h * 128 + qq * 8 + j];
            m = fmaxf(m, sc[j]);
        }
        float sum = 0.f;
        #pragma unroll
        for (int j = 0; j < 8; ++j) { sc[j] = __expf(sc[j] - m); sum += sc[j]; }
        const float inv = 0.25f / sum;
        #pragma unroll
        for (int j = 0; j < 8; ++j) sHW[(h * 16 + qq) * 9 + j] = sc[j] * inv;
    }
    __syncthreads();
    if (t < 16) {
        float at[8];
        float n2 = 0.f;
        #pragma unroll
        for (int j = 0; j < 8; ++j) {
            at[j] = sHW[(0 * 16 + t) * 9 + j] + sHW[(1 * 16 + t) * 9 + j]
                  + sHW[(2 * 16 + t) * 9 + j] + sHW[(3 * 16 + t) * 9 + j];
            n2 += at[j] * at[j];
        }
        const float nrm = fmaxf(sqrtf(n2), 1e-12f);
        #pragma unroll
        for (int j = 0; j < 8; ++j) sAW[t * 8 + j] = at[j] / nrm;
    }
    __syncthreads();

    // ---- PV: weighted sum of raw values (direct coalesced global reads) ----
    {
        const int idx = t & 15, cg = t >> 4;
        const int c8  = cg * 8;
        const float4 a0 = *(const float4*)&sAW[idx * 8];
        const float4 a1 = *(const float4*)&sAW[idx * 8 + 4];
        const float* zb = Zc + (((size_t)(b * Kc + ks)) * 128 + c8) * HWc + hp * 128 + idx * 8;
        float* ob = out + ((size_t)(b * 128 + c8)) * HWc + r0 + idx;
        #pragma unroll
        for (int i = 0; i < 8; ++i) {
            const float4 z0 = *(const float4*)(zb + (size_t)i * HWc);
            const float4 z1 = *(const float4*)(zb + (size_t)i * HWc + 4);
            ob[(size_t)i * HWc] =
                a0.x * z0.x + a0.y * z0.y + a0.z * z0.z + a0.w * z0.w +
                a1.x * z1.x + a1.y * z1.y + a1.z * z1.z + a1.w * z1.w;
        }
    }
}

// ---------------------------------------------------------------------------
extern "C" void kernel_launch(void* const* d_in, const int* in_sizes, int n_in,
                              void* d_out, int out_size, void* d_ws, size_t ws_size,
                              hipStream_t stream)
{
    const float* HFs = (const float*)d_in[0];
    const float* HFc = (const float*)d_in[1];
    const float* Zc  = (const float*)d_in[2];
    float* ws    = (float*)d_ws;
    float* zstar = (float*)d_out;
    float* zhat  = zstar + (size_t)Bc * 128 * HWc;

    prep_kernel<<<1040, 128, 0, stream>>>(
        (const float*)d_in[3],  (const float*)d_in[4],
        (const float*)d_in[5],  (const float*)d_in[6],
        (const float*)d_in[7],  (const float*)d_in[8],
        (const float*)d_in[9],  (const float*)d_in[10],
        (const float*)d_in[11], (const float*)d_in[12],
        (const float*)d_in[13], (const float*)d_in[14],
        (const float*)d_in[15], (const float*)d_in[16],
        (const float*)d_in[17], (const float*)d_in[18],
        ws);

    pack_kernel<<<192, 64, 0, stream>>>(ws);

    stage_kernel<1><<<2048, 256, 0, stream>>>(HFs, HFc, Zc, ws, zstar, zstar);
    stage_kernel<2><<<2048, 256, 0, stream>>>(HFs, HFc, Zc, ws, zstar, zhat);
}